// Round 11
// baseline (281.148 us; speedup 1.0000x reference)
//
#include <hip/hip_runtime.h>
#include <hip/hip_bf16.h>

typedef unsigned short u16;
typedef unsigned int u32;
typedef __attribute__((ext_vector_type(8))) short short8;  // bf16x8 MFMA A/B frag
typedef __attribute__((ext_vector_type(4))) float f32x4;   // MFMA acc / float4
typedef __attribute__((ext_vector_type(4))) int i32x4;     // 16B vector ld/st

__device__ __forceinline__ float b2f(u16 u) {
    union { u32 i; float f; } x; x.i = ((u32)u) << 16; return x.f;
}
__device__ __forceinline__ u16 f2b(float f) {
    union { float f; u32 u; } x; x.f = f;
    u32 r = x.u + 0x7fffu + ((x.u >> 16) & 1u);
    return (u16)(r >> 16);
}
// packed f32x2 -> bf16x2 (v_cvt_pk_bf16_f32), lo = a
__device__ __forceinline__ u32 pkbf(float a, float b) {
    union { __hip_bfloat162 h; u32 u; } x;
    x.h = __float22bfloat162_rn(make_float2(a, b));
    return x.u;
}
// async 16B global->LDS (wave-uniform LDS base + lane*16; m97 pattern)
__device__ __forceinline__ void async_cp16(const u16* g, u16* l) {
    __builtin_amdgcn_global_load_lds(
        (const __attribute__((address_space(1))) void*)g,
        (__attribute__((address_space(3))) void*)l, 16, 0, 0);
}
// hardware exp2 (v_exp_f32). NOT libm exp2f (R2 regression: ocml call path).
__device__ __forceinline__ float fexp2(float x) {
#if __has_builtin(__builtin_amdgcn_exp2f)
    return __builtin_amdgcn_exp2f(x);
#else
    return __expf(x * 0.6931471805599453f);
#endif
}
#define L2E 1.44269504f

// ---------------------------------------------------------------------------
// canon_all: merged {dtype probe + canon(x0) + canon_t(W_in) + canon_t(W_o)}.
// Grid: [0,4096) canon | [4096,4864) canon_t W_in | [4864,5120) canon_t W_o.
// ---------------------------------------------------------------------------
__global__ __launch_bounds__(256) void canon_all(
    const void* __restrict__ x0src, const void* __restrict__ wiSrc,
    const void* __restrict__ woSrc,
    u16* __restrict__ cx0, u16* __restrict__ wtin, u16* __restrict__ wto,
    int* __restrict__ flagp)
{
    __shared__ __align__(16) u16 t[64 * 72];
    const int tid = threadIdx.x;
    const int bid = blockIdx.x;

    // inline dtype probe (same semantics as old probe_dtype)
    int big = 0;
#pragma unroll
    for (int i = tid; i < 512; i += 256) {
        float v = fabsf(b2f(((const u16*)x0src)[i]));
        if (!(v <= 1e6f)) big = 1;
    }
    const int f = __syncthreads_or(big);
    if (bid == 0 && tid == 0) *flagp = f ? 1 : 0;

    if (bid < 4096) {
        // ---- canon: x0 -> cx0 (8M elems, 8/thread) ----
        int i = (bid * 256 + tid) * 8;
        if (f) {
            const float* s = (const float*)x0src + i;
            f32x4 a = *(const f32x4*)s;
            f32x4 b = *(const f32x4*)(s + 4);
            union { i32x4 v; u32 w[4]; } o;
            o.w[0] = pkbf(a[0], a[1]); o.w[1] = pkbf(a[2], a[3]);
            o.w[2] = pkbf(b[0], b[1]); o.w[3] = pkbf(b[2], b[3]);
            *(i32x4*)(cx0 + i) = o.v;
        } else {
            *(i32x4*)(cx0 + i) = *(const i32x4*)((const u16*)x0src + i);
        }
        return;
    }

    // ---- canon_t regions ----
    const void* src; u16* dst; int Mdim, Ndim, m0, n0;
    if (bid < 4096 + 768) {
        int local = bid - 4096;                  // 16 x 48
        src = wiSrc; dst = wtin; Mdim = 1024; Ndim = 3072;
        m0 = (local & 15) * 64; n0 = (local >> 4) * 64;
    } else {
        int local = bid - 4096 - 768;            // 16 x 16
        src = woSrc; dst = wto; Mdim = 1024; Ndim = 1024;
        m0 = (local & 15) * 64; n0 = (local >> 4) * 64;
    }
#pragma unroll
    for (int p = 0; p < 2; ++p) {
        int s = tid + p * 256;
        int r = s >> 3, c0 = (s & 7) << 3;
        union { i32x4 v; u32 w[4]; } o;
        if (f) {
            const float* sp = (const float*)src + (size_t)(m0 + r) * Ndim + n0 + c0;
            f32x4 a = *(const f32x4*)sp, b = *(const f32x4*)(sp + 4);
            o.w[0] = pkbf(a[0], a[1]); o.w[1] = pkbf(a[2], a[3]);
            o.w[2] = pkbf(b[0], b[1]); o.w[3] = pkbf(b[2], b[3]);
        } else {
            o.v = *(const i32x4*)((const u16*)src + (size_t)(m0 + r) * Ndim + n0 + c0);
        }
        *(i32x4*)(t + r * 72 + c0) = o.v;
    }
    __syncthreads();
#pragma unroll
    for (int p = 0; p < 2; ++p) {
        int s = tid + p * 256;
        int oc = s >> 3, mc = (s & 7) << 3;
        union { i32x4 v; u16 h[8]; } o;
#pragma unroll
        for (int j = 0; j < 8; ++j) o.h[j] = t[(mc + j) * 72 + oc];
        *(i32x4*)(dst + (size_t)(n0 + oc) * Mdim + m0 + mc) = o.v;
    }
}

// ---------------------------------------------------------------------------
// V pre-transpose: qkv[b][s][h*192+128+d] -> vT[h*64+d][b*2048+s].
// ---------------------------------------------------------------------------
__global__ __launch_bounds__(256) void vtrans(
    const u16* __restrict__ qkv, u16* __restrict__ vT)
{
    __shared__ __align__(16) u16 t[64 * 72];
    const int bh = blockIdx.x, b = bh >> 4, h = bh & 15;
    const int s0 = blockIdx.y * 64;
    const int tid = threadIdx.x;
#pragma unroll
    for (int p = 0; p < 2; ++p) {
        int s = tid + p * 256;
        int r = s >> 3, c0 = (s & 7) << 3;
        *(i32x4*)(t + r * 72 + c0) =
            *(const i32x4*)(qkv + (size_t)(b * 2048 + s0 + r) * 3072 + h * 192 + 128 + c0);
    }
    __syncthreads();
#pragma unroll
    for (int p = 0; p < 2; ++p) {
        int s = tid + p * 256;
        int oc = s >> 3, mc = (s & 7) << 3;
        union { i32x4 v; u16 h[8]; } o;
#pragma unroll
        for (int j = 0; j < 8; ++j) o.h[j] = t[(mc + j) * 72 + oc];
        *(i32x4*)(vT + (size_t)(h * 64 + oc) * 8192 + b * 2048 + s0 + mc) = o.v;
    }
}

// ---------------------------------------------------------------------------
// GEMM bp8: 256x128 tile, BK=64, 512 thr = 8 waves (4M x 2N), per-wave
// C = 64x64 (acc[4][4], proven geometry). 4 phases/K-tile a la gemm256:
//   P1: s0 x f01 (8 MFMA)   P2: s0 x f23   P3: s1 x f01   P4: s1 x f23
// ds_reads 6/2/6/2; stages spread: B(t+1)@P1 (2 loads), A(t+2)@P4 (4 loads,
// into sA[t&1] - legal: all pA reads complete at P3's end barrier).
// Counted vmcnt(4): entering tile t, A(t+1)'s 4 loads outstanding; P1 adds
// B(t+1) (2) -> 6; P4 adds A(t+2) (4) -> 10; vmcnt(4) at tile end retires
// the oldest 6 = A(t+1)+B(t+1), exactly what tile t+1 needs. Tail: vmcnt(0).
// LDS = dbuf A (2x32KB) + dbuf B (2x16KB) = 96 KB.
// Fixes gemm256's 384-block 1.5-round quantization (25% idle): grids are
// K1 768 = 3x256 and K3 256 = 1x256, both perfectly packed.
// Requires M%256==0, N%128==0, K%64==0, K/64>=2.
// ---------------------------------------------------------------------------
__global__ __launch_bounds__(512, 2) void gemm_bp8(
    const u16* __restrict__ A, const u16* __restrict__ Bt, u16* __restrict__ C,
    int M, int N, int K)
{
    __shared__ __align__(16) u16 sA[2][256 * 64];   // 64 KB
    __shared__ __align__(16) u16 sB[2][128 * 64];   // 32 KB
    const int tid  = threadIdx.x;
    const int lane = tid & 63;
    const int wave = tid >> 6;
    const int la = lane & 15;
    const int qd = lane >> 4;
    const int wm = wave >> 1;        // 0..3 (64-row band)
    const int wn = wave & 1;         // 0..1 (64-col band)

    // L2-locality mapping: 4M x 8N super-tile per XCD-round (R7, verified)
    const int x = blockIdx.x & 7;          // XCD (dispatch round-robin)
    const int q = blockIdx.x >> 3;
    const int r = q >> 5;                  // N-round (8 Ntiles per round)
    const int p = q & 31;                  // position in 4M x 8N super-tile
    const int m0 = (x * 4 + (p & 3)) * 256;
    const int n0 = (r * 8 + (p >> 2)) * 128;

    const int srow = tid >> 3;                         // 0..63
    const int scol = (((tid & 7) ^ (srow & 7)) << 3);  // u16 units
    const int nt = K >> 6;

    const u16* gA = A  + (size_t)(m0 + srow) * K + scol;
    const u16* gB = Bt + (size_t)(n0 + srow) * K + scol;

    auto stageA = [&](int tk) {            // 4 loads -> sA[tk&1]
        u16* dst = &sA[tk & 1][0] + tid * 8;
        const u16* g = gA + tk * 64;
#pragma unroll
        for (int h = 0; h < 4; ++h)
            async_cp16(g + (size_t)(h * 64) * K, dst + h * 4096);
    };
    auto stageB = [&](int tk) {            // 2 loads -> sB[tk&1]
        u16* dst = &sB[tk & 1][0] + tid * 8;
        const u16* g = gB + tk * 64;
#pragma unroll
        for (int h = 0; h < 2; ++h)
            async_cp16(g + (size_t)(h * 64) * K, dst + h * 4096);
    };

    f32x4 acc[4][4];
    const f32x4 fz = {0.f, 0.f, 0.f, 0.f};
#pragma unroll
    for (int i = 0; i < 4; ++i)
#pragma unroll
        for (int j = 0; j < 4; ++j) acc[i][j] = fz;

    // prologue: A(0),B(0),A(1) = 10 loads; drain tile0, keep A(1) in flight.
    stageA(0); stageB(0); stageA(1);
    asm volatile("s_waitcnt vmcnt(4)" ::: "memory");
    __builtin_amdgcn_s_barrier();

    const int swk = la & 7;   // read-side chunk XOR key (row&7 == la&7)

    for (int t = 0; t < nt; ++t) {
        const u16* pA = &sA[t & 1][0];
        const u16* pB = &sB[t & 1][0];
        short8 af[4], bf[2];

        // ---------------- P1: s0 x f01 ----------------
#pragma unroll
        for (int i = 0; i < 4; ++i)
            af[i] = *(const short8*)(pA + (wm * 64 + i * 16 + la) * 64 +
                                     ((qd ^ swk) << 3));
#pragma unroll
        for (int f = 0; f < 2; ++f)
            bf[f] = *(const short8*)(pB + (wn * 64 + f * 16 + la) * 64 +
                                     ((qd ^ swk) << 3));
        if (t + 1 < nt) stageB(t + 1);
        __builtin_amdgcn_s_barrier();
        asm volatile("s_waitcnt lgkmcnt(0)" ::: "memory");
        __builtin_amdgcn_s_setprio(1);
#pragma unroll
        for (int i = 0; i < 4; ++i)
#pragma unroll
            for (int f = 0; f < 2; ++f)
                acc[i][f] = __builtin_amdgcn_mfma_f32_16x16x32_bf16(
                    af[i], bf[f], acc[i][f], 0, 0, 0);
        __builtin_amdgcn_s_setprio(0);
        __builtin_amdgcn_s_barrier();

        // ---------------- P2: s0 x f23 ----------------
#pragma unroll
        for (int f = 0; f < 2; ++f)
            bf[f] = *(const short8*)(pB + (wn * 64 + (2 + f) * 16 + la) * 64 +
                                     ((qd ^ swk) << 3));
        __builtin_amdgcn_s_barrier();
        asm volatile("s_waitcnt lgkmcnt(0)" ::: "memory");
        __builtin_amdgcn_s_setprio(1);
#pragma unroll
        for (int i = 0; i < 4; ++i)
#pragma unroll
            for (int f = 0; f < 2; ++f)
                acc[i][2 + f] = __builtin_amdgcn_mfma_f32_16x16x32_bf16(
                    af[i], bf[f], acc[i][2 + f], 0, 0, 0);
        __builtin_amdgcn_s_setprio(0);
        __builtin_amdgcn_s_barrier();

        // ---------------- P3: s1 x f01 ----------------
#pragma unroll
        for (int i = 0; i < 4; ++i)
            af[i] = *(const short8*)(pA + (wm * 64 + i * 16 + la) * 64 +
                                     (((4 + qd) ^ swk) << 3));
#pragma unroll
        for (int f = 0; f < 2; ++f)
            bf[f] = *(const short8*)(pB + (wn * 64 + f * 16 + la) * 64 +
                                     (((4 + qd) ^ swk) << 3));
        __builtin_amdgcn_s_barrier();
        asm volatile("s_waitcnt lgkmcnt(0)" ::: "memory");
        __builtin_amdgcn_s_setprio(1);
#pragma unroll
        for (int i = 0; i < 4; ++i)
#pragma unroll
            for (int f = 0; f < 2; ++f)
                acc[i][f] = __builtin_amdgcn_mfma_f32_16x16x32_bf16(
                    af[i], bf[f], acc[i][f], 0, 0, 0);
        __builtin_amdgcn_s_setprio(0);
        __builtin_amdgcn_s_barrier();

        // ---------------- P4: s1 x f23 ----------------
#pragma unroll
        for (int f = 0; f < 2; ++f)
            bf[f] = *(const short8*)(pB + (wn * 64 + (2 + f) * 16 + la) * 64 +
                                     (((4 + qd) ^ swk) << 3));
        if (t + 2 < nt) stageA(t + 2);   // into sA[t&1]; pA reads done @P3 end
        __builtin_amdgcn_s_barrier();
        asm volatile("s_waitcnt lgkmcnt(0)" ::: "memory");
        __builtin_amdgcn_s_setprio(1);
#pragma unroll
        for (int i = 0; i < 4; ++i)
#pragma unroll
            for (int f = 0; f < 2; ++f)
                acc[i][2 + f] = __builtin_amdgcn_mfma_f32_16x16x32_bf16(
                    af[i], bf[f], acc[i][2 + f], 0, 0, 0);
        __builtin_amdgcn_s_setprio(0);
        if (t + 2 < nt)      asm volatile("s_waitcnt vmcnt(4)" ::: "memory");
        else if (t + 1 < nt) asm volatile("s_waitcnt vmcnt(0)" ::: "memory");
        __builtin_amdgcn_s_barrier();
    }

    // epilogue
#pragma unroll
    for (int fi = 0; fi < 4; ++fi)
#pragma unroll
        for (int fj = 0; fj < 4; ++fj)
#pragma unroll
            for (int r2 = 0; r2 < 4; ++r2) {
                int row = m0 + wm * 64 + fi * 16 + qd * 4 + r2;
                int col = n0 + wn * 64 + fj * 16 + la;
                C[(size_t)row * N + col] = f2b(acc[fi][fj][r2]);
            }
}

// ---------------------------------------------------------------------------
// MFMA flash attention v10 (unchanged from round 10, verified): 8-wave
// blocks (512 thr), 128 q-rows per seg, single-call staging, defer-max,
// hw-exp2 softmax, max3 tree, deferred l-reduction.
// ---------------------------------------------------------------------------
#define S_LEN 2048
#define D3 3072
#define NEG_BIG (-30000.0f)

__global__ __launch_bounds__(512, 4) void attn_fwd(
    const u16* __restrict__ qkv, const u16* __restrict__ vT,
    u16* __restrict__ outp)
{
    __shared__ __align__(16) u16 Ks[2 * 64 * 64];   // [buf][kcol][d]  16 KB
    __shared__ __align__(16) u16 Vts[2 * 64 * 64];  // [buf][d][kcol]  16 KB
    __shared__ __align__(16) u16 Ps[128 * 64];      // [q][kcol]       16 KB
    const int tid  = threadIdx.x;
    const int lane = tid & 63;
    const int wave = tid >> 6;       // 0..7
    const int la = lane & 15;
    const int qd = lane >> 4;
    // XCD grouping: 8 blocks of one bh land on one XCD
    const int lin = blockIdx.y * 8 + blockIdx.x;   // grid (8, 64)
    const int xcd = lin & 7, idx = lin >> 3;
    const int bh = xcd * 8 + (idx >> 3);
    const int px = idx & 7;                  // pair index 0..7
    const int b = bh >> 4, h = bh & 15;
    const size_t rowb = (size_t)b * S_LEN * D3;
    const int hq = h * 192;
    const u16* vTp = vT + (size_t)(h * 64) * 8192 + (size_t)b * 2048;
    const f32x4 fz = {0.f, 0.f, 0.f, 0.f};

    // staging: 512 threads cover one 64x64 bf16 tile (8KB) in ONE call.
    const int srow = tid >> 3;
    const int scol = ((tid & 7) ^ (srow & 7)) << 3;                 // u16
    const u16* gK = qkv + rowb + (size_t)srow * D3 + hq + 64 + scol;
    const u16* gV = vTp + (size_t)srow * 8192 + scol;

    const int swz = (la & 7);   // read-side chunk XOR key (row&7 == la&7)

    int cur = 0;
#pragma unroll
    for (int seg = 0; seg < 2; ++seg) {
        const int qtU = seg == 0 ? 2 * px + 1 : 31 - 2 * px;  // upper q-tile
        const int q0  = (qtU - 1) * 64;                        // 128-row base
        const int qg  = q0 + wave * 16 + la;   // this lane's q-row

        // Q fragments in registers, scaled by 0.125 (exact pow2 in bf16)
        short8 bq[2];
#pragma unroll
        for (int s = 0; s < 2; ++s) {
            union { short8 v; u16 h[8]; } u;
            u.v = *(const short8*)(qkv + rowb + (size_t)qg * D3 + hq + s * 32 + qd * 8);
#pragma unroll
            for (int j = 0; j < 8; ++j) u.h[j] = f2b(b2f(u.h[j]) * 0.125f);
            bq[s] = u.v;
        }

        f32x4 Oacc[4];
#pragma unroll
        for (int jd = 0; jd < 4; ++jd) Oacc[jd] = fz;
        float m_run = NEG_BIG, l_part = 0.f;

        __syncthreads();   // all waves done reading LDS (prev seg)
        // prologue: stage tile 0 into buf[cur] (one call per buffer)
        async_cp16(gK, Ks + cur * 4096 + tid * 8);
        async_cp16(gV, Vts + cur * 4096 + tid * 8);

        for (int kt = 0; kt <= qtU; ++kt) {
            const int k0 = kt * 64;
            __syncthreads();   // drains vmcnt: buf[cur] staged; prev reads done
            if (kt < qtU) {    // prefetch next tile into buf[cur^1]
                const int kn = k0 + 64;
                async_cp16(gK + (size_t)kn * D3, Ks + (cur ^ 1) * 4096 + tid * 8);
                async_cp16(gV + kn, Vts + (cur ^ 1) * 4096 + tid * 8);
            }
            const u16* KsC  = Ks  + cur * 4096;
            const u16* VtsC = Vts + cur * 4096;

            // ---- S^T = K . Q^T ----
            f32x4 sacc[4];
#pragma unroll
            for (int jm = 0; jm < 4; ++jm) sacc[jm] = fz;
            __builtin_amdgcn_s_setprio(1);
#pragma unroll
            for (int s = 0; s < 2; ++s) {
#pragma unroll
                for (int jm = 0; jm < 4; ++jm) {
                    short8 ak = *(const short8*)(KsC + (jm * 16 + la) * 64 +
                                                 (((s * 4 + qd) ^ swz) << 3));
                    sacc[jm] = __builtin_amdgcn_mfma_f32_16x16x32_bf16(ak, bq[s], sacc[jm], 0, 0, 0);
                }
            }
            __builtin_amdgcn_s_setprio(0);
            if (kt + 1 >= qtU) {   // boundary tiles: causal mask (per-row)
#pragma unroll
                for (int jm = 0; jm < 4; ++jm)
#pragma unroll
                    for (int r = 0; r < 4; ++r)
                        if (k0 + jm * 16 + qd * 4 + r > qg) sacc[jm][r] = NEG_BIG;
            }

            // ---- softmax: v_max3 triples + 2 shuffles over qd ----
            float g0 = fmaxf(fmaxf(sacc[0][0], sacc[0][1]), sacc[0][2]);
            float g1 = fmaxf(fmaxf(sacc[0][3], sacc[1][0]), sacc[1][1]);
            float g2 = fmaxf(fmaxf(sacc[1][2], sacc[1][3]), sacc[2][0]);
            float g3 = fmaxf(fmaxf(sacc[2][1], sacc[2][2]), sacc[2][3]);
            float g4 = fmaxf(fmaxf(sacc[3][0], sacc[3][1]), sacc[3][2]);
            float mx = fmaxf(fmaxf(fmaxf(g0, g1), g2),
                             fmaxf(fmaxf(g3, g4), sacc[3][3]));
            mx = fmaxf(mx, __shfl_xor(mx, 16));
            mx = fmaxf(mx, __shfl_xor(mx, 32));

            // T13 defer-max: only rescale when tile max meaningfully exceeds m_run
            const int skip = __all(mx <= m_run + 4.0f);
            if (!skip) {
                float mnew = fmaxf(m_run, mx);
                float al   = fexp2((m_run - mnew) * L2E);
                float ar[4];
#pragma unroll
                for (int r = 0; r < 4; ++r) ar[r] = __shfl(al, qd * 4 + r);
#pragma unroll
                for (int jd = 0; jd < 4; ++jd)
#pragma unroll
                    for (int r = 0; r < 4; ++r) Oacc[jd][r] *= ar[r];
                l_part *= al;
                m_run = mnew;
            }
            // p = exp2(s*L2E - m*L2E): one v_fma + one v_exp per element
            const float nm2 = m_run * L2E;
            float ssum = 0.f;
#pragma unroll
            for (int jm = 0; jm < 4; ++jm)
#pragma unroll
                for (int r = 0; r < 4; ++r) {
                    float pv = fexp2(fmaf(sacc[jm][r], L2E, -nm2));
                    sacc[jm][r] = pv;
                    ssum += pv;
                }
            l_part += ssum;   // cross-lane reduction deferred to epilogue

            // ---- P -> LDS (packed cvt + b64 writes, wave-private rows) ----
#pragma unroll
            for (int jm = 0; jm < 4; ++jm) {
                uint2 w;
                w.x = pkbf(sacc[jm][0], sacc[jm][1]);
                w.y = pkbf(sacc[jm][2], sacc[jm][3]);
                *(uint2*)(Ps + (wave * 16 + la) * 64 +
                          ((((jm * 2 + (qd >> 1)) ^ swz)) << 3) + ((qd & 1) << 2)) = w;
            }

            // ---- PV ----
            __builtin_amdgcn_s_setprio(1);
#pragma unroll
            for (int s = 0; s < 2; ++s) {
                short8 ap = *(const short8*)(Ps + (wave * 16 + la) * 64 +
                                             (((s * 4 + qd) ^ swz) << 3));
#pragma unroll
                for (int jd = 0; jd < 4; ++jd) {
                    short8 bv = *(const short8*)(VtsC + (jd * 16 + la) * 64 +
                                                 (((s * 4 + qd) ^ swz) << 3));
                    Oacc[jd] = __builtin_amdgcn_mfma_f32_16x16x32_bf16(ap, bv, Oacc[jd], 0, 0, 0);
                }
            }
            __builtin_amdgcn_s_setprio(0);
            cur ^= 1;
        }

        // epilogue: reduce l across qd group (deferred), then normalize+store
        float lt = l_part;
        lt += __shfl_xor(lt, 16);
        lt += __shfl_xor(lt, 32);
#pragma unroll
        for (int r = 0; r < 4; ++r) {
            float lr = __shfl(lt, qd * 4 + r);
            float inv = 1.f / lr;
            size_t orow = (size_t)(b * S_LEN + q0 + wave * 16 + qd * 4 + r) * 1024 + h * 64;
#pragma unroll
            for (int jd = 0; jd < 4; ++jd)
                outp[orow + jd * 16 + la] = f2b(Oacc[jd][r] * inv);
        }
    }
}

// ---------------------------------------------------------------------------
// y = proj + x0 ; LayerNorm over last dim (1024). Output dtype per wire flag.
// ---------------------------------------------------------------------------
__global__ __launch_bounds__(256) void ln_residual(
    const u16* __restrict__ proj, const u16* __restrict__ x0,
    void* __restrict__ out, const int* __restrict__ flag)
{
    __shared__ float red[8];
    __shared__ float stats[2];
    const size_t base = (size_t)blockIdx.x * 1024 + threadIdx.x * 4;
    union { uint2 u; u16 s[4]; } pa, xa;
    pa.u = *(const uint2*)(proj + base);
    xa.u = *(const uint2*)(x0 + base);
    float y[4];
    float s1 = 0.f, s2 = 0.f;
#pragma unroll
    for (int j = 0; j < 4; ++j) {
        y[j] = b2f(pa.s[j]) + b2f(xa.s[j]);
        s1 += y[j];
        s2 += y[j] * y[j];
    }
#pragma unroll
    for (int off = 32; off > 0; off >>= 1) {
        s1 += __shfl_down(s1, off);
        s2 += __shfl_down(s2, off);
    }
    const int wave = threadIdx.x >> 6, lane = threadIdx.x & 63;
    if (lane == 0) { red[wave * 2] = s1; red[wave * 2 + 1] = s2; }
    __syncthreads();
    if (threadIdx.x == 0) {
        float S1 = red[0] + red[2] + red[4] + red[6];
        float S2 = red[1] + red[3] + red[5] + red[7];
        float mean = S1 * (1.f / 1024.f);
        float var  = fmaxf(S2 * (1.f / 1024.f) - mean * mean, 0.f);
        stats[0] = mean;
        stats[1] = rsqrtf(var + 1e-5f);
    }
    __syncthreads();
    float mean = stats[0], inv = stats[1];
    if (*flag) {
        f32x4 o;
#pragma unroll
        for (int j = 0; j < 4; ++j) o[j] = (y[j] - mean) * inv;
        *(f32x4*)((float*)out + base) = o;
    } else {
        union { uint2 u; u16 s[4]; } o;
#pragma unroll
        for (int j = 0; j < 4; ++j) o.s[j] = f2b((y[j] - mean) * inv);
        *(uint2*)((u16*)out + base) = o.u;
    }
}

// ---------------------------------------------------------------------------
extern "C" void kernel_launch(void* const* d_in, const int* in_sizes, int n_in,
                              void* d_out, int out_size, void* d_ws, size_t ws_size,
                              hipStream_t stream) {
    // d_in[3] = src_mask, all-False per spec -> ignored
    char* ws = (char*)d_ws;
    int* flag = (int*)ws;
    u16* cx0  = (u16*)(ws + 256);                 // 8192x1024  bf16 (16 MB)
    u16* wtin = cx0  + (size_t)8192 * 1024;       // W_in^T [3072][1024] (6 MB)
    u16* wto  = wtin + (size_t)3072 * 1024;       // W_o^T  [1024][1024] (2 MB)
    u16* qkv  = wto  + (size_t)1024 * 1024;       // 8192x3072 (48 MB)
    u16* vT   = qkv  + (size_t)8192 * 3072;       // [16*64][8192] (16 MB)
    u16* attn = vT   + (size_t)1024 * 8192;       // 8192x1024 (16 MB)
    u16* proj = qkv;                              // reuse qkv region (K3 after K2)

    dim3 blk(256);
    // K0: merged probe + canon + canon_t x2
    canon_all<<<dim3(4096 + 768 + 256), blk, 0, stream>>>(
        d_in[0], d_in[1], d_in[2], cx0, wtin, wto, flag);
    // K1: QKV projection — 4-phase 256x128, 768 blocks = exactly 3 CU-waves
    gemm_bp8<<<dim3(768), dim3(512), 0, stream>>>(cx0, wtin, qkv, 8192, 3072, 1024);
    // V pre-transpose
    vtrans<<<dim3(64, 32), blk, 0, stream>>>(qkv, vT);
    // K2: causal flash attention — v10: 8-wave blocks, 128 q-rows/seg
    attn_fwd<<<dim3(8, 64), dim3(512), 0, stream>>>(qkv, vT, attn);
    // K3: output projection — 4-phase 256x128, 256 blocks = 1 full CU-wave
    gemm_bp8<<<dim3(256), dim3(512), 0, stream>>>(attn, wto, proj, 8192, 1024, 1024);
    // K4: residual + LayerNorm
    ln_residual<<<dim3(8192), blk, 0, stream>>>(proj, cx0, d_out, flag);
}

// Round 12
// 257.822 us; speedup vs baseline: 1.0905x; 1.0905x over previous
//
#include <hip/hip_runtime.h>
#include <hip/hip_bf16.h>

typedef unsigned short u16;
typedef unsigned int u32;
typedef __attribute__((ext_vector_type(8))) short short8;  // bf16x8 MFMA A/B frag
typedef __attribute__((ext_vector_type(4))) float f32x4;   // MFMA acc / float4
typedef __attribute__((ext_vector_type(4))) int i32x4;     // 16B vector ld/st

__device__ __forceinline__ float b2f(u16 u) {
    union { u32 i; float f; } x; x.i = ((u32)u) << 16; return x.f;
}
__device__ __forceinline__ u16 f2b(float f) {
    union { float f; u32 u; } x; x.f = f;
    u32 r = x.u + 0x7fffu + ((x.u >> 16) & 1u);
    return (u16)(r >> 16);
}
// packed f32x2 -> bf16x2 (v_cvt_pk_bf16_f32), lo = a
__device__ __forceinline__ u32 pkbf(float a, float b) {
    union { __hip_bfloat162 h; u32 u; } x;
    x.h = __float22bfloat162_rn(make_float2(a, b));
    return x.u;
}
// async 16B global->LDS (wave-uniform LDS base + lane*16; m97 pattern)
__device__ __forceinline__ void async_cp16(const u16* g, u16* l) {
    __builtin_amdgcn_global_load_lds(
        (const __attribute__((address_space(1))) void*)g,
        (__attribute__((address_space(3))) void*)l, 16, 0, 0);
}
// hardware exp2 (v_exp_f32). NOT libm exp2f (R2 regression: ocml call path).
__device__ __forceinline__ float fexp2(float x) {
#if __has_builtin(__builtin_amdgcn_exp2f)
    return __builtin_amdgcn_exp2f(x);
#else
    return __expf(x * 0.6931471805599453f);
#endif
}
#define L2E 1.44269504f

// ---------------------------------------------------------------------------
// canon_all: merged {dtype probe + canon(x0) + canon_t(W_in) + canon_t(W_o)}.
// Grid: [0,4096) canon | [4096,4864) canon_t W_in | [4864,5120) canon_t W_o.
// ---------------------------------------------------------------------------
__global__ __launch_bounds__(256) void canon_all(
    const void* __restrict__ x0src, const void* __restrict__ wiSrc,
    const void* __restrict__ woSrc,
    u16* __restrict__ cx0, u16* __restrict__ wtin, u16* __restrict__ wto,
    int* __restrict__ flagp)
{
    __shared__ __align__(16) u16 t[64 * 72];
    const int tid = threadIdx.x;
    const int bid = blockIdx.x;

    // inline dtype probe (same semantics as old probe_dtype)
    int big = 0;
#pragma unroll
    for (int i = tid; i < 512; i += 256) {
        float v = fabsf(b2f(((const u16*)x0src)[i]));
        if (!(v <= 1e6f)) big = 1;
    }
    const int f = __syncthreads_or(big);
    if (bid == 0 && tid == 0) *flagp = f ? 1 : 0;

    if (bid < 4096) {
        // ---- canon: x0 -> cx0 (8M elems, 8/thread) ----
        int i = (bid * 256 + tid) * 8;
        if (f) {
            const float* s = (const float*)x0src + i;
            f32x4 a = *(const f32x4*)s;
            f32x4 b = *(const f32x4*)(s + 4);
            union { i32x4 v; u32 w[4]; } o;
            o.w[0] = pkbf(a[0], a[1]); o.w[1] = pkbf(a[2], a[3]);
            o.w[2] = pkbf(b[0], b[1]); o.w[3] = pkbf(b[2], b[3]);
            *(i32x4*)(cx0 + i) = o.v;
        } else {
            *(i32x4*)(cx0 + i) = *(const i32x4*)((const u16*)x0src + i);
        }
        return;
    }

    // ---- canon_t regions ----
    const void* src; u16* dst; int Mdim, Ndim, m0, n0;
    if (bid < 4096 + 768) {
        int local = bid - 4096;                  // 16 x 48
        src = wiSrc; dst = wtin; Mdim = 1024; Ndim = 3072;
        m0 = (local & 15) * 64; n0 = (local >> 4) * 64;
    } else {
        int local = bid - 4096 - 768;            // 16 x 16
        src = woSrc; dst = wto; Mdim = 1024; Ndim = 1024;
        m0 = (local & 15) * 64; n0 = (local >> 4) * 64;
    }
#pragma unroll
    for (int p = 0; p < 2; ++p) {
        int s = tid + p * 256;
        int r = s >> 3, c0 = (s & 7) << 3;
        union { i32x4 v; u32 w[4]; } o;
        if (f) {
            const float* sp = (const float*)src + (size_t)(m0 + r) * Ndim + n0 + c0;
            f32x4 a = *(const f32x4*)sp, b = *(const f32x4*)(sp + 4);
            o.w[0] = pkbf(a[0], a[1]); o.w[1] = pkbf(a[2], a[3]);
            o.w[2] = pkbf(b[0], b[1]); o.w[3] = pkbf(b[2], b[3]);
        } else {
            o.v = *(const i32x4*)((const u16*)src + (size_t)(m0 + r) * Ndim + n0 + c0);
        }
        *(i32x4*)(t + r * 72 + c0) = o.v;
    }
    __syncthreads();
#pragma unroll
    for (int p = 0; p < 2; ++p) {
        int s = tid + p * 256;
        int oc = s >> 3, mc = (s & 7) << 3;
        union { i32x4 v; u16 h[8]; } o;
#pragma unroll
        for (int j = 0; j < 8; ++j) o.h[j] = t[(mc + j) * 72 + oc];
        *(i32x4*)(dst + (size_t)(n0 + oc) * Mdim + m0 + mc) = o.v;
    }
}

// ---------------------------------------------------------------------------
// V pre-transpose: qkv[b][s][h*192+128+d] -> vT[h*64+d][b*2048+s].
// ---------------------------------------------------------------------------
__global__ __launch_bounds__(256) void vtrans(
    const u16* __restrict__ qkv, u16* __restrict__ vT)
{
    __shared__ __align__(16) u16 t[64 * 72];
    const int bh = blockIdx.x, b = bh >> 4, h = bh & 15;
    const int s0 = blockIdx.y * 64;
    const int tid = threadIdx.x;
#pragma unroll
    for (int p = 0; p < 2; ++p) {
        int s = tid + p * 256;
        int r = s >> 3, c0 = (s & 7) << 3;
        *(i32x4*)(t + r * 72 + c0) =
            *(const i32x4*)(qkv + (size_t)(b * 2048 + s0 + r) * 3072 + h * 192 + 128 + c0);
    }
    __syncthreads();
#pragma unroll
    for (int p = 0; p < 2; ++p) {
        int s = tid + p * 256;
        int oc = s >> 3, mc = (s & 7) << 3;
        union { i32x4 v; u16 h[8]; } o;
#pragma unroll
        for (int j = 0; j < 8; ++j) o.h[j] = t[(mc + j) * 72 + oc];
        *(i32x4*)(vT + (size_t)(h * 64 + oc) * 8192 + b * 2048 + s0 + mc) = o.v;
    }
}

// ---------------------------------------------------------------------------
// GEMM bp: 256x128 tile, BK=64, 8 waves (4M x 2N), per-wave C = 64x64.
// 2-phase; A triple-buffered, B double-buffered; vmcnt(4). 756 TF-eq/round.
// ldc = C row stride (C may be a column slab of a wider matrix).
// Grid must be 256 blocks x k rounds; covers N = (grid/32)*128 columns.
// ---------------------------------------------------------------------------
__global__ __launch_bounds__(512, 2) void gemm_bp(
    const u16* __restrict__ A, const u16* __restrict__ Bt, u16* __restrict__ C,
    int M, int ldc, int K)
{
    __shared__ __align__(16) u16 sA0[256 * 64], sA1[256 * 64], sA2[256 * 64];
    __shared__ __align__(16) u16 sB0[128 * 64], sB1[128 * 64];
    const int tid  = threadIdx.x;
    const int lane = tid & 63;
    const int wave = tid >> 6;
    const int la = lane & 15;
    const int qd = lane >> 4;
    const int wm = wave >> 1;        // 0..3 (64-row band)
    const int wn = wave & 1;         // 0..1 (64-col band)

    // L2-locality mapping: 4M x 8N super-tile per XCD-round (R7, verified)
    const int x = blockIdx.x & 7;          // XCD (dispatch round-robin)
    const int q = blockIdx.x >> 3;
    const int r = q >> 5;                  // N-round (8 Ntiles per round)
    const int p = q & 31;                  // position in 4M x 8N super-tile
    const int m0 = (x * 4 + (p & 3)) * 256;
    const int n0 = (r * 8 + (p >> 2)) * 128;

    const int srow = tid >> 3;                         // 0..63
    const int scol = (((tid & 7) ^ (srow & 7)) << 3);  // u16 units
    const int nt = K >> 6;

    const u16* gA = A  + (size_t)(m0 + srow) * K + scol;
    const u16* gB = Bt + (size_t)(n0 + srow) * K + scol;

    auto stageA = [&](int tk, u16* buf) {
        u16* dst = buf + tid * 8;
        const u16* g = gA + tk * 64;
#pragma unroll
        for (int h = 0; h < 4; ++h)
            async_cp16(g + (size_t)(h * 64) * K, dst + h * 64 * 64);
    };
    auto stageB = [&](int tk, u16* buf) {
        u16* dst = buf + tid * 8;
        const u16* g = gB + tk * 64;
#pragma unroll
        for (int h = 0; h < 2; ++h)
            async_cp16(g + (size_t)(h * 64) * K, dst + h * 64 * 64);
    };

    f32x4 acc[4][4];
    const f32x4 fz = {0.f, 0.f, 0.f, 0.f};
#pragma unroll
    for (int i = 0; i < 4; ++i)
#pragma unroll
        for (int j = 0; j < 4; ++j) acc[i][j] = fz;

    u16 *aCur = sA0, *aNxt = sA1, *aNN = sA2;
    u16 *bCur = sB0, *bNxt = sB1;

    stageA(0, aCur); stageB(0, bCur); stageA(1, aNxt);
    asm volatile("s_waitcnt vmcnt(4)" ::: "memory");
    __builtin_amdgcn_s_barrier();

    const int swk = la & 7;   // read-side chunk XOR key (row&7 == la&7)

    for (int t = 0; t < nt; ++t) {
        // ---------------- P1: k-slice 0 ----------------
        short8 a0[4], b0[4];
#pragma unroll
        for (int f = 0; f < 4; ++f)
            a0[f] = *(const short8*)(aCur + (wm * 64 + f * 16 + la) * 64 +
                                     ((qd ^ swk) << 3));
#pragma unroll
        for (int f = 0; f < 4; ++f)
            b0[f] = *(const short8*)(bCur + (wn * 64 + f * 16 + la) * 64 +
                                     ((qd ^ swk) << 3));
        if (t + 1 < nt) stageB(t + 1, bNxt);
        if (t + 2 < nt) stageA(t + 2, aNN);
        __builtin_amdgcn_s_barrier();
        asm volatile("s_waitcnt lgkmcnt(0)" ::: "memory");
        __builtin_amdgcn_s_setprio(1);
#pragma unroll
        for (int i = 0; i < 4; ++i)
#pragma unroll
            for (int j = 0; j < 4; ++j)
                acc[i][j] = __builtin_amdgcn_mfma_f32_16x16x32_bf16(
                    a0[i], b0[j], acc[i][j], 0, 0, 0);
        __builtin_amdgcn_s_setprio(0);
        __builtin_amdgcn_s_barrier();

        // ---------------- P2: k-slice 1 ----------------
        short8 a1[4], b1[4];
#pragma unroll
        for (int f = 0; f < 4; ++f)
            a1[f] = *(const short8*)(aCur + (wm * 64 + f * 16 + la) * 64 +
                                     (((4 + qd) ^ swk) << 3));
#pragma unroll
        for (int f = 0; f < 4; ++f)
            b1[f] = *(const short8*)(bCur + (wn * 64 + f * 16 + la) * 64 +
                                     (((4 + qd) ^ swk) << 3));
        __builtin_amdgcn_s_barrier();
        asm volatile("s_waitcnt lgkmcnt(0)" ::: "memory");
        __builtin_amdgcn_s_setprio(1);
#pragma unroll
        for (int i = 0; i < 4; ++i)
#pragma unroll
            for (int j = 0; j < 4; ++j)
                acc[i][j] = __builtin_amdgcn_mfma_f32_16x16x32_bf16(
                    a1[i], b1[j], acc[i][j], 0, 0, 0);
        __builtin_amdgcn_s_setprio(0);
        if (t + 2 < nt)      asm volatile("s_waitcnt vmcnt(4)" ::: "memory");
        else if (t + 1 < nt) asm volatile("s_waitcnt vmcnt(0)" ::: "memory");
        __builtin_amdgcn_s_barrier();

        u16* tmp = aCur; aCur = aNxt; aNxt = aNN; aNN = tmp;
        tmp = bCur; bCur = bNxt; bNxt = tmp;
    }

    // epilogue
#pragma unroll
    for (int fi = 0; fi < 4; ++fi)
#pragma unroll
        for (int fj = 0; fj < 4; ++fj)
#pragma unroll
            for (int r2 = 0; r2 < 4; ++r2) {
                int row = m0 + wm * 64 + fi * 16 + qd * 4 + r2;
                int col = n0 + wn * 64 + fj * 16 + la;
                C[(size_t)row * ldc + col] = f2b(acc[fi][fj][r2]);
            }
}

// ---------------------------------------------------------------------------
// GEMM 256x256 8-phase + L2 super-tile mapping. 936 TF-eq/round (measured
// R10). ldc = C row stride. Grid must be 256 blocks x k rounds; covers
// N = (grid/32)*256 columns.
// ---------------------------------------------------------------------------
__global__ __launch_bounds__(512, 2) void gemm256(
    const u16* __restrict__ A, const u16* __restrict__ Bt, u16* __restrict__ C,
    int M, int ldc, int K)
{
    __shared__ __align__(16) u16 sA[2][256 * 64];   // 64 KB
    __shared__ __align__(16) u16 sB[2][256 * 64];   // 64 KB
    const int tid  = threadIdx.x;
    const int lane = tid & 63;
    const int wave = tid >> 6;
    const int la = lane & 15;
    const int qd = lane >> 4;
    const int wm = wave >> 2;        // 0..1
    const int wn = wave & 3;         // 0..3

    // L2-locality mapping: 4M x 8N super-tile per XCD-round
    const int x = blockIdx.x & 7;
    const int q = blockIdx.x >> 3;
    const int r = q >> 5;
    const int p = q & 31;
    const int m0 = (x * 4 + (p & 3)) * 256;
    const int n0 = (r * 8 + (p >> 2)) * 256;

    const int srow = tid >> 3;                         // 0..63
    const int scol = (((tid & 7) ^ (srow & 7)) << 3);  // u16 units
    const int nt = K >> 6;

    auto stageA = [&](int tk, int half) {
        u16* dst = &sA[tk & 1][half * 128 * 64] + tid * 8;
        const u16* g = A + (size_t)(m0 + half * 128 + srow) * K + tk * 64 + scol;
        async_cp16(g, dst);
        async_cp16(g + (size_t)64 * K, dst + 64 * 64);
    };
    auto stageB = [&](int tk, int half) {
        u16* dst = &sB[tk & 1][half * 128 * 64] + tid * 8;
        const u16* g = Bt + (size_t)(n0 + half * 128 + srow) * K + tk * 64 + scol;
        async_cp16(g, dst);
        async_cp16(g + (size_t)64 * K, dst + 64 * 64);
    };

    f32x4 acc[8][4];
    const f32x4 fz = {0.f, 0.f, 0.f, 0.f};
#pragma unroll
    for (int i = 0; i < 8; ++i)
#pragma unroll
        for (int j = 0; j < 4; ++j) acc[i][j] = fz;

    stageA(0, 0); stageA(0, 1); stageB(0, 0); stageB(0, 1);
    stageA(1, 0); stageA(1, 1);
    asm volatile("s_waitcnt vmcnt(4)" ::: "memory");
    __builtin_amdgcn_s_barrier();

    const int swk = (la & 7);   // read-side chunk XOR key (row&7 == la&7)

#pragma unroll 2
    for (int t = 0; t < nt; ++t) {
        const u16* pA = &sA[t & 1][0];
        const u16* pB = &sB[t & 1][0];
        short8 a0[2][4], a1[2][4], b0[2][2], b1[2][2];

        // ---------------- P1 ----------------
#pragma unroll
        for (int s = 0; s < 2; ++s) {
#pragma unroll
            for (int f = 0; f < 4; ++f)
                a0[s][f] = *(const short8*)(pA + (wm * 128 + f * 16 + la) * 64 +
                                            (((s * 4 + qd) ^ swk) << 3));
#pragma unroll
            for (int f = 0; f < 2; ++f)
                b0[s][f] = *(const short8*)(pB + (wn * 64 + f * 16 + la) * 64 +
                                            (((s * 4 + qd) ^ swk) << 3));
        }
        if (t + 1 < nt) stageB(t + 1, 0);
        __builtin_amdgcn_s_barrier();
        asm volatile("s_waitcnt lgkmcnt(0)" ::: "memory");
        __builtin_amdgcn_s_setprio(1);
#pragma unroll
        for (int s = 0; s < 2; ++s)
#pragma unroll
            for (int f = 0; f < 4; ++f)
#pragma unroll
                for (int j = 0; j < 2; ++j)
                    acc[f][j] = __builtin_amdgcn_mfma_f32_16x16x32_bf16(
                        a0[s][f], b0[s][j], acc[f][j], 0, 0, 0);
        __builtin_amdgcn_s_setprio(0);
        __builtin_amdgcn_s_barrier();

        // ---------------- P2 ----------------
#pragma unroll
        for (int s = 0; s < 2; ++s)
#pragma unroll
            for (int f = 0; f < 4; ++f)
                a1[s][f] = *(const short8*)(pA + (wm * 128 + (4 + f) * 16 + la) * 64 +
                                            (((s * 4 + qd) ^ swk) << 3));
        if (t + 1 < nt) stageB(t + 1, 1);
        __builtin_amdgcn_s_barrier();
        asm volatile("s_waitcnt lgkmcnt(0)" ::: "memory");
        __builtin_amdgcn_s_setprio(1);
#pragma unroll
        for (int s = 0; s < 2; ++s)
#pragma unroll
            for (int f = 0; f < 4; ++f)
#pragma unroll
                for (int j = 0; j < 2; ++j)
                    acc[4 + f][j] = __builtin_amdgcn_mfma_f32_16x16x32_bf16(
                        a1[s][f], b0[s][j], acc[4 + f][j], 0, 0, 0);
        __builtin_amdgcn_s_setprio(0);
        __builtin_amdgcn_s_barrier();

        // ---------------- P3 ----------------
#pragma unroll
        for (int s = 0; s < 2; ++s)
#pragma unroll
            for (int f = 0; f < 2; ++f)
                b1[s][f] = *(const short8*)(pB + (wn * 64 + (2 + f) * 16 + la) * 64 +
                                            (((s * 4 + qd) ^ swk) << 3));
        if (t + 2 < nt) stageA(t + 2, 0);
        __builtin_amdgcn_s_barrier();
        asm volatile("s_waitcnt lgkmcnt(0)" ::: "memory");
        __builtin_amdgcn_s_setprio(1);
#pragma unroll
        for (int s = 0; s < 2; ++s)
#pragma unroll
            for (int f = 0; f < 4; ++f)
#pragma unroll
                for (int j = 0; j < 2; ++j)
                    acc[f][2 + j] = __builtin_amdgcn_mfma_f32_16x16x32_bf16(
                        a0[s][f], b1[s][j], acc[f][2 + j], 0, 0, 0);
        __builtin_amdgcn_s_setprio(0);
        __builtin_amdgcn_s_barrier();

        // ---------------- P4 ----------------
        if (t + 2 < nt) stageA(t + 2, 1);
        __builtin_amdgcn_s_barrier();
        __builtin_amdgcn_s_setprio(1);
#pragma unroll
        for (int s = 0; s < 2; ++s)
#pragma unroll
            for (int f = 0; f < 4; ++f)
#pragma unroll
                for (int j = 0; j < 2; ++j)
                    acc[4 + f][2 + j] = __builtin_amdgcn_mfma_f32_16x16x32_bf16(
                        a1[s][f], b1[s][j], acc[4 + f][2 + j], 0, 0, 0);
        __builtin_amdgcn_s_setprio(0);
        if (t + 2 < nt)      asm volatile("s_waitcnt vmcnt(4)" ::: "memory");
        else if (t + 1 < nt) asm volatile("s_waitcnt vmcnt(0)" ::: "memory");
        __builtin_amdgcn_s_barrier();
    }

    // epilogue
#pragma unroll
    for (int fi = 0; fi < 8; ++fi)
#pragma unroll
        for (int fj = 0; fj < 4; ++fj)
#pragma unroll
            for (int r2 = 0; r2 < 4; ++r2) {
                int row = m0 + wm * 128 + fi * 16 + qd * 4 + r2;
                int col = n0 + wn * 64 + fj * 16 + la;
                C[(size_t)row * ldc + col] = f2b(acc[fi][fj][r2]);
            }
}

// ---------------------------------------------------------------------------
// MFMA flash attention v10 (unchanged, verified R10): 8-wave blocks
// (512 thr), 128 q-rows per seg, single-call staging, defer-max,
// hw-exp2 softmax, max3 tree, deferred l-reduction.
// ---------------------------------------------------------------------------
#define S_LEN 2048
#define D3 3072
#define NEG_BIG (-30000.0f)

__global__ __launch_bounds__(512, 4) void attn_fwd(
    const u16* __restrict__ qkv, const u16* __restrict__ vT,
    u16* __restrict__ outp)
{
    __shared__ __align__(16) u16 Ks[2 * 64 * 64];   // [buf][kcol][d]  16 KB
    __shared__ __align__(16) u16 Vts[2 * 64 * 64];  // [buf][d][kcol]  16 KB
    __shared__ __align__(16) u16 Ps[128 * 64];      // [q][kcol]       16 KB
    const int tid  = threadIdx.x;
    const int lane = tid & 63;
    const int wave = tid >> 6;       // 0..7
    const int la = lane & 15;
    const int qd = lane >> 4;
    // XCD grouping: 8 blocks of one bh land on one XCD
    const int lin = blockIdx.y * 8 + blockIdx.x;   // grid (8, 64)
    const int xcd = lin & 7, idx = lin >> 3;
    const int bh = xcd * 8 + (idx >> 3);
    const int px = idx & 7;                  // pair index 0..7
    const int b = bh >> 4, h = bh & 15;
    const size_t rowb = (size_t)b * S_LEN * D3;
    const int hq = h * 192;
    const u16* vTp = vT + (size_t)(h * 64) * 8192 + (size_t)b * 2048;
    const f32x4 fz = {0.f, 0.f, 0.f, 0.f};

    // staging: 512 threads cover one 64x64 bf16 tile (8KB) in ONE call.
    const int srow = tid >> 3;
    const int scol = ((tid & 7) ^ (srow & 7)) << 3;                 // u16
    const u16* gK = qkv + rowb + (size_t)srow * D3 + hq + 64 + scol;
    const u16* gV = vTp + (size_t)srow * 8192 + scol;

    const int swz = (la & 7);   // read-side chunk XOR key (row&7 == la&7)

    int cur = 0;
#pragma unroll
    for (int seg = 0; seg < 2; ++seg) {
        const int qtU = seg == 0 ? 2 * px + 1 : 31 - 2 * px;  // upper q-tile
        const int q0  = (qtU - 1) * 64;                        // 128-row base
        const int qg  = q0 + wave * 16 + la;   // this lane's q-row

        // Q fragments in registers, scaled by 0.125 (exact pow2 in bf16)
        short8 bq[2];
#pragma unroll
        for (int s = 0; s < 2; ++s) {
            union { short8 v; u16 h[8]; } u;
            u.v = *(const short8*)(qkv + rowb + (size_t)qg * D3 + hq + s * 32 + qd * 8);
#pragma unroll
            for (int j = 0; j < 8; ++j) u.h[j] = f2b(b2f(u.h[j]) * 0.125f);
            bq[s] = u.v;
        }

        f32x4 Oacc[4];
#pragma unroll
        for (int jd = 0; jd < 4; ++jd) Oacc[jd] = fz;
        float m_run = NEG_BIG, l_part = 0.f;

        __syncthreads();   // all waves done reading LDS (prev seg)
        // prologue: stage tile 0 into buf[cur] (one call per buffer)
        async_cp16(gK, Ks + cur * 4096 + tid * 8);
        async_cp16(gV, Vts + cur * 4096 + tid * 8);

        for (int kt = 0; kt <= qtU; ++kt) {
            const int k0 = kt * 64;
            __syncthreads();   // drains vmcnt: buf[cur] staged; prev reads done
            if (kt < qtU) {    // prefetch next tile into buf[cur^1]
                const int kn = k0 + 64;
                async_cp16(gK + (size_t)kn * D3, Ks + (cur ^ 1) * 4096 + tid * 8);
                async_cp16(gV + kn, Vts + (cur ^ 1) * 4096 + tid * 8);
            }
            const u16* KsC  = Ks  + cur * 4096;
            const u16* VtsC = Vts + cur * 4096;

            // ---- S^T = K . Q^T ----
            f32x4 sacc[4];
#pragma unroll
            for (int jm = 0; jm < 4; ++jm) sacc[jm] = fz;
            __builtin_amdgcn_s_setprio(1);
#pragma unroll
            for (int s = 0; s < 2; ++s) {
#pragma unroll
                for (int jm = 0; jm < 4; ++jm) {
                    short8 ak = *(const short8*)(KsC + (jm * 16 + la) * 64 +
                                                 (((s * 4 + qd) ^ swz) << 3));
                    sacc[jm] = __builtin_amdgcn_mfma_f32_16x16x32_bf16(ak, bq[s], sacc[jm], 0, 0, 0);
                }
            }
            __builtin_amdgcn_s_setprio(0);
            if (kt + 1 >= qtU) {   // boundary tiles: causal mask (per-row)
#pragma unroll
                for (int jm = 0; jm < 4; ++jm)
#pragma unroll
                    for (int r = 0; r < 4; ++r)
                        if (k0 + jm * 16 + qd * 4 + r > qg) sacc[jm][r] = NEG_BIG;
            }

            // ---- softmax: v_max3 triples + 2 shuffles over qd ----
            float g0 = fmaxf(fmaxf(sacc[0][0], sacc[0][1]), sacc[0][2]);
            float g1 = fmaxf(fmaxf(sacc[0][3], sacc[1][0]), sacc[1][1]);
            float g2 = fmaxf(fmaxf(sacc[1][2], sacc[1][3]), sacc[2][0]);
            float g3 = fmaxf(fmaxf(sacc[2][1], sacc[2][2]), sacc[2][3]);
            float g4 = fmaxf(fmaxf(sacc[3][0], sacc[3][1]), sacc[3][2]);
            float mx = fmaxf(fmaxf(fmaxf(g0, g1), g2),
                             fmaxf(fmaxf(g3, g4), sacc[3][3]));
            mx = fmaxf(mx, __shfl_xor(mx, 16));
            mx = fmaxf(mx, __shfl_xor(mx, 32));

            // T13 defer-max: only rescale when tile max meaningfully exceeds m_run
            const int skip = __all(mx <= m_run + 4.0f);
            if (!skip) {
                float mnew = fmaxf(m_run, mx);
                float al   = fexp2((m_run - mnew) * L2E);
                float ar[4];
#pragma unroll
                for (int r = 0; r < 4; ++r) ar[r] = __shfl(al, qd * 4 + r);
#pragma unroll
                for (int jd = 0; jd < 4; ++jd)
#pragma unroll
                    for (int r = 0; r < 4; ++r) Oacc[jd][r] *= ar[r];
                l_part *= al;
                m_run = mnew;
            }
            // p = exp2(s*L2E - m*L2E): one v_fma + one v_exp per element
            const float nm2 = m_run * L2E;
            float ssum = 0.f;
#pragma unroll
            for (int jm = 0; jm < 4; ++jm)
#pragma unroll
                for (int r = 0; r < 4; ++r) {
                    float pv = fexp2(fmaf(sacc[jm][r], L2E, -nm2));
                    sacc[jm][r] = pv;
                    ssum += pv;
                }
            l_part += ssum;   // cross-lane reduction deferred to epilogue

            // ---- P -> LDS (packed cvt + b64 writes, wave-private rows) ----
#pragma unroll
            for (int jm = 0; jm < 4; ++jm) {
                uint2 w;
                w.x = pkbf(sacc[jm][0], sacc[jm][1]);
                w.y = pkbf(sacc[jm][2], sacc[jm][3]);
                *(uint2*)(Ps + (wave * 16 + la) * 64 +
                          ((((jm * 2 + (qd >> 1)) ^ swz)) << 3) + ((qd & 1) << 2)) = w;
            }

            // ---- PV ----
            __builtin_amdgcn_s_setprio(1);
#pragma unroll
            for (int s = 0; s < 2; ++s) {
                short8 ap = *(const short8*)(Ps + (wave * 16 + la) * 64 +
                                             (((s * 4 + qd) ^ swz) << 3));
#pragma unroll
                for (int jd = 0; jd < 4; ++jd) {
                    short8 bv = *(const short8*)(VtsC + (jd * 16 + la) * 64 +
                                                 (((s * 4 + qd) ^ swz) << 3));
                    Oacc[jd] = __builtin_amdgcn_mfma_f32_16x16x32_bf16(ap, bv, Oacc[jd], 0, 0, 0);
                }
            }
            __builtin_amdgcn_s_setprio(0);
            cur ^= 1;
        }

        // epilogue: reduce l across qd group (deferred), then normalize+store
        float lt = l_part;
        lt += __shfl_xor(lt, 16);
        lt += __shfl_xor(lt, 32);
#pragma unroll
        for (int r = 0; r < 4; ++r) {
            float lr = __shfl(lt, qd * 4 + r);
            float inv = 1.f / lr;
            size_t orow = (size_t)(b * S_LEN + q0 + wave * 16 + qd * 4 + r) * 1024 + h * 64;
#pragma unroll
            for (int jd = 0; jd < 4; ++jd)
                outp[orow + jd * 16 + la] = f2b(Oacc[jd][r] * inv);
        }
    }
}

// ---------------------------------------------------------------------------
// y = proj + x0 ; LayerNorm over last dim (1024). Output dtype per wire flag.
// ---------------------------------------------------------------------------
__global__ __launch_bounds__(256) void ln_residual(
    const u16* __restrict__ proj, const u16* __restrict__ x0,
    void* __restrict__ out, const int* __restrict__ flag)
{
    __shared__ float red[8];
    __shared__ float stats[2];
    const size_t base = (size_t)blockIdx.x * 1024 + threadIdx.x * 4;
    union { uint2 u; u16 s[4]; } pa, xa;
    pa.u = *(const uint2*)(proj + base);
    xa.u = *(const uint2*)(x0 + base);
    float y[4];
    float s1 = 0.f, s2 = 0.f;
#pragma unroll
    for (int j = 0; j < 4; ++j) {
        y[j] = b2f(pa.s[j]) + b2f(xa.s[j]);
        s1 += y[j];
        s2 += y[j] * y[j];
    }
#pragma unroll
    for (int off = 32; off > 0; off >>= 1) {
        s1 += __shfl_down(s1, off);
        s2 += __shfl_down(s2, off);
    }
    const int wave = threadIdx.x >> 6, lane = threadIdx.x & 63;
    if (lane == 0) { red[wave * 2] = s1; red[wave * 2 + 1] = s2; }
    __syncthreads();
    if (threadIdx.x == 0) {
        float S1 = red[0] + red[2] + red[4] + red[6];
        float S2 = red[1] + red[3] + red[5] + red[7];
        float mean = S1 * (1.f / 1024.f);
        float var  = fmaxf(S2 * (1.f / 1024.f) - mean * mean, 0.f);
        stats[0] = mean;
        stats[1] = rsqrtf(var + 1e-5f);
    }
    __syncthreads();
    float mean = stats[0], inv = stats[1];
    if (*flag) {
        f32x4 o;
#pragma unroll
        for (int j = 0; j < 4; ++j) o[j] = (y[j] - mean) * inv;
        *(f32x4*)((float*)out + base) = o;
    } else {
        union { uint2 u; u16 s[4]; } o;
#pragma unroll
        for (int j = 0; j < 4; ++j) o.s[j] = f2b((y[j] - mean) * inv);
        *(uint2*)((u16*)out + base) = o.u;
    }
}

// ---------------------------------------------------------------------------
extern "C" void kernel_launch(void* const* d_in, const int* in_sizes, int n_in,
                              void* d_out, int out_size, void* d_ws, size_t ws_size,
                              hipStream_t stream) {
    // d_in[3] = src_mask, all-False per spec -> ignored
    char* ws = (char*)d_ws;
    int* flag = (int*)ws;
    u16* cx0  = (u16*)(ws + 256);                 // 8192x1024  bf16 (16 MB)
    u16* wtin = cx0  + (size_t)8192 * 1024;       // W_in^T [3072][1024] (6 MB)
    u16* wto  = wtin + (size_t)3072 * 1024;       // W_o^T  [1024][1024] (2 MB)
    u16* qkv  = wto  + (size_t)1024 * 1024;       // 8192x3072 (48 MB)
    u16* vT   = qkv  + (size_t)8192 * 3072;       // [16*64][8192] (16 MB)
    u16* attn = vT   + (size_t)1024 * 8192;       // 8192x1024 (16 MB)
    u16* proj = qkv;                              // reuse qkv region (K3 after K2)

    dim3 blk(256);
    // K0: merged probe + canon + canon_t x2
    canon_all<<<dim3(4096 + 768 + 256), blk, 0, stream>>>(
        d_in[0], d_in[1], d_in[2], cx0, wtin, wto, flag);
    // K1a: QKV cols 0..2047 — gemm256 (936 TF-eq), 256 blocks = 1 full round
    gemm256<<<dim3(256), dim3(512), 0, stream>>>(
        cx0, wtin, qkv, 8192, 3072, 1024);
    // K1b: QKV cols 2048..3071 — gemm_bp (756 TF-eq), 256 blocks = 1 round
    gemm_bp<<<dim3(256), dim3(512), 0, stream>>>(
        cx0, wtin + (size_t)2048 * 1024, qkv + 2048, 8192, 3072, 1024);
    // V pre-transpose
    vtrans<<<dim3(64, 32), blk, 0, stream>>>(qkv, vT);
    // K2: causal flash attention — v10: 8-wave blocks, 128 q-rows/seg
    attn_fwd<<<dim3(8, 64), dim3(512), 0, stream>>>(qkv, vT, attn);
    // K3: output projection — gemm_bp, 256 blocks = 1 full round
    gemm_bp<<<dim3(256), dim3(512), 0, stream>>>(attn, wto, proj, 8192, 1024, 1024);
    // K4: residual + LayerNorm
    ln_residual<<<dim3(8192), blk, 0, stream>>>(proj, cx0, d_out, flag);
}